// Round 4
// baseline (151.606 us; speedup 1.0000x reference)
//
#include <hip/hip_runtime.h>
#include <hip/hip_bf16.h>
#include <math.h>

#define B 8
#define CIN 12
#define CQ 36
#define CP 48               // channel dim padded: 36 data + 2 logL + 10 zero
#define N 4096
#define SCALE 0.28867513459481287f   // 1/sqrt(12)
#define LOG2E 1.4426950408889634f
#define ZSPLIT 16
#define NCHUNK (N / ZSPLIT) // 256
#define NT (NCHUNK / 32)    // 8 tiles per attn WG (single-staged chunk)
#define MSPLIT 4

typedef __attribute__((ext_vector_type(4)))  short bf4_t;
typedef __attribute__((ext_vector_type(8)))  short bf8_t;
typedef __attribute__((ext_vector_type(16))) float f32x16;
typedef __attribute__((ext_vector_type(4)))  float f32x4;

__device__ __forceinline__ unsigned short f2bf(float x) {
  unsigned int u = __float_as_uint(x);
  u += 0x7FFFu + ((u >> 16) & 1u);   // RNE
  return (unsigned short)(u >> 16);
}

#if __has_builtin(__builtin_amdgcn_cvt_pk_bf16_f32)
typedef __attribute__((ext_vector_type(2))) __bf16 bf16x2_t;
__device__ __forceinline__ unsigned pk2bf(float a, float b) {
  bf16x2_t v = __builtin_amdgcn_cvt_pk_bf16_f32(a, b);
  return __builtin_bit_cast(unsigned, v);
}
#else
__device__ __forceinline__ unsigned pk2bf(float a, float b) {
  return (__float_as_uint(a) >> 16) | (__float_as_uint(b) & 0xFFFF0000u);
}
#endif

__device__ __forceinline__ float bf2f(unsigned short u) {
  return __uint_as_float((unsigned)u << 16);
}

__device__ __forceinline__ float exp2fast(float x) {
#if __has_builtin(__builtin_amdgcn_exp2f)
  return __builtin_amdgcn_exp2f(x);
#else
  return exp2f(x);
#endif
}

// 16x16x16 quad-K MFMA (verified R4-R7): A[m=l15][k=q4*4+i], B[k][n=l15],
// D col=l15 row=q4*4+r.
__device__ __forceinline__ f32x4 mfma16(bf4_t a, bf4_t b, f32x4 c) {
#if __has_builtin(__builtin_amdgcn_mfma_f32_16x16x16bf16_1k)
  return __builtin_amdgcn_mfma_f32_16x16x16bf16_1k(a, b, c, 0, 0, 0);
#else
  bf8_t a8 = {a[0], a[1], a[2], a[3], 0, 0, 0, 0};
  bf8_t b8 = {b[0], b[1], b[2], b[3], 0, 0, 0, 0};
  return __builtin_amdgcn_mfma_f32_16x16x32_bf16(a8, b8, c, 0, 0, 0);
#endif
}

// 16B LDS access helpers for 8B-aligned addresses (rows padded to 104/520 B)
__device__ __forceinline__ bf8_t lds_bf8(const unsigned short* p) {
  uint2 a = *(const uint2*)p;
  uint2 b = *(const uint2*)(p + 4);
  uint4 r{a.x, a.y, b.x, b.y};
  return __builtin_bit_cast(bf8_t, r);
}
__device__ __forceinline__ void wlds16(unsigned short* p, uint4 v) {
  *(uint2*)p = uint2{v.x, v.y};
  *(uint2*)(p + 4) = uint2{v.z, v.w};
}

// ---------------- QKV projection (y=0..2) + out bias init (y=3) -----------
__global__ __launch_bounds__(256) void qkv_kernel(
    const float* __restrict__ x,
    const float* __restrict__ wq, const float* __restrict__ bq,
    const float* __restrict__ wk, const float* __restrict__ bk,
    const float* __restrict__ wv, const float* __restrict__ bv,
    const float* __restrict__ bo,
    unsigned short* __restrict__ qT, unsigned short* __restrict__ kT,
    unsigned short* __restrict__ vbf, float* __restrict__ out) {
  __shared__ float sw[CQ * CIN];
  __shared__ float sb[CQ];
  int z = blockIdx.y;   // 0->q, 1->k (scaled), 2->v, 3->bias-init of out
  int tid = threadIdx.x;
  if (z == 3) {
    // init out[b][i][n] = bo[i]; B*CIN*N/4 float4 over 128 blocks, 3 each
#pragma unroll
    for (int r = 0; r < 3; ++r) {
      int gid4 = blockIdx.x * 256 + tid + r * 32768;
      int e4 = gid4 * 4;
      int i = (e4 >> 12) % CIN;
      float bvv = bo[i];
      *(float4*)(out + e4) = float4{bvv, bvv, bvv, bvv};
    }
    return;
  }
  const float* w  = (z == 0) ? wq : (z == 1) ? wk : wv;
  const float* bb = (z == 0) ? bq : (z == 1) ? bk : bv;
  float scale = (z == 1) ? SCALE * LOG2E : 1.0f;
  for (int e = tid; e < CQ * CIN; e += 256) sw[e] = w[e] * scale;
  if (tid < CQ) sb[tid] = bb[tid] * scale;
  __syncthreads();
  int gid = blockIdx.x * 256 + tid;    // over B*N
  int b = gid >> 12;
  int n = gid & (N - 1);
  float xv[CIN];
#pragma unroll
  for (int i = 0; i < CIN; ++i) xv[i] = x[(b * CIN + i) * N + n];
  if (z == 2) {
#pragma unroll
    for (int o = 0; o < CQ; ++o) {
      float a = sb[o];
#pragma unroll
      for (int i = 0; i < CIN; ++i) a += sw[o * CIN + i] * xv[i];
      vbf[((size_t)b * CP + o) * N + n] = f2bf(a);
    }
  } else {
    __attribute__((aligned(16))) unsigned row[CP / 2];
#pragma unroll
    for (int o = 0; o < CQ; o += 2) {
      float a0 = sb[o], a1 = sb[o + 1];
#pragma unroll
      for (int i = 0; i < CIN; ++i) {
        float xi = xv[i];
        a0 += sw[o * CIN + i] * xi;
        a1 += sw[(o + 1) * CIN + i] * xi;
      }
      row[o / 2] = (unsigned)f2bf(a0) | ((unsigned)f2bf(a1) << 16);
    }
    row[18] = (z == 0) ? 0x3F803F80u : 0u;  // q: ch36/37=1.0; k: patched in attn
#pragma unroll
    for (int o = 19; o < CP / 2; ++o) row[o] = 0;
    unsigned short* dst = ((z == 0) ? qT : kT) + ((size_t)b * N + n) * CP;
#pragma unroll
    for (int i = 0; i < 6; ++i) *(uint4*)(dst + 8 * i) = *(const uint4*)&row[4 * i];
  }
}

// ---------------- Pass 1: psum[ms][b][n], MSPLIT=4 m-slices ---------------
__global__ __launch_bounds__(256) void stats_kernel(
    const unsigned short* __restrict__ qT, const unsigned short* __restrict__ kT,
    float* __restrict__ psum) {
  __shared__ float red[4][64];
  int tid = threadIdx.x, lane = tid & 63, wave = tid >> 6;
  int b = blockIdx.y, nblk = blockIdx.x, ms = blockIdx.z;
  int l31 = lane & 31, h = lane >> 5;
  int n0 = nblk * 64;
  size_t bN = (size_t)b * N;
  const unsigned short* krow0 = kT + (bN + n0 + l31) * CP + h * 8;
  const unsigned short* krow1 = krow0 + (size_t)32 * CP;
  bf8_t a0 = *(const bf8_t*)(krow0);
  bf8_t a1 = *(const bf8_t*)(krow0 + 16);
  bf8_t a2 = *(const bf8_t*)(krow0 + 32);
  bf8_t a3 = *(const bf8_t*)(krow1);
  bf8_t a4 = *(const bf8_t*)(krow1 + 16);
  bf8_t a5 = *(const bf8_t*)(krow1 + 32);
  float rs0[16], rs1[16];
#pragma unroll
  for (int r = 0; r < 16; ++r) { rs0[r] = 0.f; rs1[r] = 0.f; }
  const int MW = N / MSPLIT / 4;   // 256 m per wave
  const unsigned short* qbase =
      qT + (bN + ms * (N / MSPLIT) + wave * MW + l31) * CP + h * 8;
#pragma unroll 2
  for (int t = 0; t < MW / 32; ++t) {
    const unsigned short* qrow2 = qbase + (size_t)t * 32 * CP;
    bf8_t b0 = *(const bf8_t*)(qrow2);
    bf8_t b1 = *(const bf8_t*)(qrow2 + 16);
    bf8_t b2 = *(const bf8_t*)(qrow2 + 32);
    f32x16 S0, S1;
#pragma unroll
    for (int r = 0; r < 16; ++r) { S0[r] = 0.f; S1[r] = 0.f; }
    S0 = __builtin_amdgcn_mfma_f32_32x32x16_bf16(a0, b0, S0, 0, 0, 0);
    S0 = __builtin_amdgcn_mfma_f32_32x32x16_bf16(a1, b1, S0, 0, 0, 0);
    S0 = __builtin_amdgcn_mfma_f32_32x32x16_bf16(a2, b2, S0, 0, 0, 0);
    S1 = __builtin_amdgcn_mfma_f32_32x32x16_bf16(a3, b0, S1, 0, 0, 0);
    S1 = __builtin_amdgcn_mfma_f32_32x32x16_bf16(a4, b1, S1, 0, 0, 0);
    S1 = __builtin_amdgcn_mfma_f32_32x32x16_bf16(a5, b2, S1, 0, 0, 0);
#pragma unroll
    for (int r = 0; r < 16; ++r) {
      rs0[r] += exp2fast(S0[r]);
      rs1[r] += exp2fast(S1[r]);
    }
  }
#pragma unroll
  for (int off = 16; off >= 1; off >>= 1)
#pragma unroll
    for (int r = 0; r < 16; ++r) {
      rs0[r] += __shfl_xor(rs0[r], off, 32);
      rs1[r] += __shfl_xor(rs1[r], off, 32);
    }
  if (l31 == 0) {
#pragma unroll
    for (int r = 0; r < 16; ++r) {
      int row = (r & 3) + 8 * (r >> 2) + 4 * h;   // 32x32 C/D row map
      red[wave][row] = rs0[r];
      red[wave][32 + row] = rs1[r];
    }
  }
  __syncthreads();
  if (tid < 64) {
    float s = red[0][tid] + red[1][tid] + red[2][tid] + red[3][tid];
    psum[((size_t)ms * B + b) * N + n0 + tid] = s;
  }
}

// ---------------- Pass 2: stage-once attn, barrier-free tile loop ----------
__global__ __launch_bounds__(256, 2) void attn_kernel(
    const unsigned short* __restrict__ qT, const unsigned short* __restrict__ kT,
    const unsigned short* __restrict__ vbf, const float* __restrict__ wo,
    const float* __restrict__ psum, float* __restrict__ out) {
  __shared__ unsigned short kbuf[NCHUNK * 52];        // [n][48+pad4]  26624 B
  __shared__ unsigned short vbuf[48 * (NCHUNK + 4)];  // [c][256+pad4] 24960 B
  __shared__ unsigned short plds[4][2][32 * 40];      // per-wave P^T  20480 B
  int tid = threadIdx.x, lane = tid & 63, wave = tid >> 6;
  int b = blockIdx.y, z = blockIdx.z, mblk = blockIdx.x;
  int l31 = lane & 31, h = lane >> 5, l15 = lane & 15, q4 = lane >> 4;
  int m0 = mblk * 256 + wave * 64;
  size_t bN = (size_t)b * N;
  int n0 = z * NCHUNK;
  // ---- stage whole K/V chunk: 12 uint4 per thread, all loads batched ----
  uint4 sv[12];
  const unsigned short* ksrc = kT + (bN + n0) * CP;   // 256 rows x 96B, contiguous
#pragma unroll
  for (int j = 0; j < 6; ++j) {        // k items: idx = j*256+tid
    int idx = j * 256 + tid;
    int row = idx / 6, c = idx % 6;
    sv[j] = *(const uint4*)(ksrc + (size_t)row * CP + c * 8);
  }
#pragma unroll
  for (int j = 0; j < 6; ++j) {        // v items: 48 rows x 32 uint4
    int vi = j * 256 + tid;
    int row = vi >> 5, c = vi & 31;
    sv[6 + j] = *(const uint4*)(vbf + ((size_t)b * CP + row) * N + n0 + c * 8);
  }
  // logL: k items whose uint4 covers ch32..39 (c==4) get -log2(L) hi/lo in .z
#pragma unroll
  for (int j = 0; j < 6; ++j) {
    int idx = j * 256 + tid;
    int row = idx / 6, c = idx % 6;
    if (c == 4) {
      const float* pL = psum + bN + n0 + row;
      float Lp = pL[0] + pL[(size_t)B * N] + pL[2 * (size_t)B * N] +
                 pL[3 * (size_t)B * N];
      float tl = -__log2f(Lp);
      unsigned short hi = f2bf(tl);
      unsigned short lo = f2bf(tl - bf2f(hi));
      sv[j].z = (unsigned)hi | ((unsigned)lo << 16);
    }
  }
#pragma unroll
  for (int j = 0; j < 6; ++j) {
    int idx = j * 256 + tid;
    int row = idx / 6, c = idx % 6;
    wlds16(&kbuf[row * 52 + c * 8], sv[j]);
  }
#pragma unroll
  for (int j = 0; j < 6; ++j) {
    int vi = j * 256 + tid;
    int row = vi >> 5, c = vi & 31;
    wlds16(&vbuf[row * (NCHUNK + 4) + c * 8], sv[6 + j]);
  }
  // q B-frags for two m-tiles (loop-invariant), incl ch36/37 = 1.0
  bf8_t qb[2][3];
#pragma unroll
  for (int mt = 0; mt < 2; ++mt) {
    const unsigned short* qrow = qT + (bN + m0 + mt * 32 + l31) * CP + h * 8;
    qb[mt][0] = *(const bf8_t*)(qrow);
    qb[mt][1] = *(const bf8_t*)(qrow + 16);
    qb[mt][2] = *(const bf8_t*)(qrow + 32);
  }
  // wo A-frags: A[i=l15][k=16ct+q4*4+j], zero outside 12x36
  bf4_t woa[3];
#pragma unroll
  for (int ct = 0; ct < 3; ++ct) {
    float4 w4 = {0.f, 0.f, 0.f, 0.f};
    int col = 16 * ct + q4 * 4;
    if (l15 < CIN && col < CQ) w4 = *(const float4*)(wo + l15 * CQ + col);
    woa[ct] = bf4_t{(short)f2bf(w4.x), (short)f2bf(w4.y),
                    (short)f2bf(w4.z), (short)f2bf(w4.w)};
  }
  f32x4 acc[2][3][2];
#pragma unroll
  for (int mt = 0; mt < 2; ++mt)
#pragma unroll
    for (int ct = 0; ct < 3; ++ct)
#pragma unroll
      for (int hm = 0; hm < 2; ++hm)
#pragma unroll
        for (int r = 0; r < 4; ++r) acc[mt][ct][hm][r] = 0.f;
  __syncthreads();   // the ONLY block-wide barrier: chunk staged, read-only below
  for (int t = 0; t < NT; ++t) {
    const unsigned short* kb = kbuf + t * 32 * 52;
    const unsigned short* vb = vbuf + t * 32;
    bf8_t a0 = lds_bf8(kb + l31 * 52 + h * 8);
    bf8_t a1 = lds_bf8(kb + l31 * 52 + h * 8 + 16);
    bf8_t a2 = lds_bf8(kb + l31 * 52 + h * 8 + 32);
    // two independent S -> exp -> pack chains (plds is wave-private)
#pragma unroll
    for (int mt = 0; mt < 2; ++mt) {
      f32x16 S;
#pragma unroll
      for (int r = 0; r < 16; ++r) S[r] = 0.f;
      S = __builtin_amdgcn_mfma_f32_32x32x16_bf16(a0, qb[mt][0], S, 0, 0, 0);
      S = __builtin_amdgcn_mfma_f32_32x32x16_bf16(a1, qb[mt][1], S, 0, 0, 0);
      S = __builtin_amdgcn_mfma_f32_32x32x16_bf16(a2, qb[mt][2], S, 0, 0, 0);
      unsigned short* pl = plds[wave][mt];
#pragma unroll
      for (int qd = 0; qd < 4; ++qd) {
        uint2 pk;
        pk.x = pk2bf(exp2fast(S[4 * qd + 0]), exp2fast(S[4 * qd + 1]));
        pk.y = pk2bf(exp2fast(S[4 * qd + 2]), exp2fast(S[4 * qd + 3]));
        *(uint2*)&pl[l31 * 40 + 8 * qd + 4 * h] = pk;
      }
    }
    bf8_t v0 = lds_bf8(vb + (0 * 16 + l15) * (NCHUNK + 4) + q4 * 8);
    bf8_t v1 = lds_bf8(vb + (1 * 16 + l15) * (NCHUNK + 4) + q4 * 8);
    bf8_t v2 = lds_bf8(vb + (2 * 16 + l15) * (NCHUNK + 4) + q4 * 8);
#pragma unroll
    for (int mt = 0; mt < 2; ++mt) {
      const unsigned short* pl = plds[wave][mt];
      bf8_t pb0 = *(const bf8_t*)&pl[l15 * 40 + q4 * 8];
      bf8_t pb1 = *(const bf8_t*)&pl[(16 + l15) * 40 + q4 * 8];
      acc[mt][0][0] = __builtin_amdgcn_mfma_f32_16x16x32_bf16(v0, pb0, acc[mt][0][0], 0, 0, 0);
      acc[mt][0][1] = __builtin_amdgcn_mfma_f32_16x16x32_bf16(v0, pb1, acc[mt][0][1], 0, 0, 0);
      acc[mt][1][0] = __builtin_amdgcn_mfma_f32_16x16x32_bf16(v1, pb0, acc[mt][1][0], 0, 0, 0);
      acc[mt][1][1] = __builtin_amdgcn_mfma_f32_16x16x32_bf16(v1, pb1, acc[mt][1][1], 0, 0, 0);
      acc[mt][2][0] = __builtin_amdgcn_mfma_f32_16x16x32_bf16(v2, pb0, acc[mt][2][0], 0, 0, 0);
      acc[mt][2][1] = __builtin_amdgcn_mfma_f32_16x16x32_bf16(v2, pb1, acc[mt][2][1], 0, 0, 0);
    }
    // no barrier: kbuf/vbuf are read-only, plds is wave-private
  }
  // fused projection: acc tile (C-layout) == quad-K B-operand layout
#pragma unroll
  for (int mt = 0; mt < 2; ++mt)
#pragma unroll
    for (int hm = 0; hm < 2; ++hm) {
      f32x4 po = {0.f, 0.f, 0.f, 0.f};
#pragma unroll
      for (int ct = 0; ct < 3; ++ct) {
        union { uint2 u; bf4_t v; } pb;
        pb.u.x = pk2bf(acc[mt][ct][hm][0], acc[mt][ct][hm][1]);
        pb.u.y = pk2bf(acc[mt][ct][hm][2], acc[mt][ct][hm][3]);
        po = mfma16(woa[ct], pb.v, po);
      }
      if (q4 < 3) {
        float* ob = out + ((size_t)b * CIN + q4 * 4) * N + m0 + mt * 32 + hm * 16 + l15;
#pragma unroll
        for (int r = 0; r < 4; ++r) atomicAdd(ob + (size_t)r * N, po[r]);
      }
    }
}

extern "C" void kernel_launch(void* const* d_in, const int* in_sizes, int n_in,
                              void* d_out, int out_size, void* d_ws, size_t ws_size,
                              hipStream_t stream) {
  const float* x  = (const float*)d_in[0];
  const float* wq = (const float*)d_in[1];
  const float* bq = (const float*)d_in[2];
  const float* wk = (const float*)d_in[3];
  const float* bk = (const float*)d_in[4];
  const float* wv = (const float*)d_in[5];
  const float* bv = (const float*)d_in[6];
  const float* wo = (const float*)d_in[7];
  const float* bo = (const float*)d_in[8];
  float* out = (float*)d_out;

  char* ws = (char*)d_ws;
  unsigned short* qT  = (unsigned short*)ws;                 // 3,145,728 B
  unsigned short* kT  = (unsigned short*)(ws + 3145728);     // 3,145,728 B
  unsigned short* vbf = (unsigned short*)(ws + 2 * 3145728); // 3,145,728 B
  float* psum = (float*)(ws + 3 * 3145728);                  //   524,288 B (MSPLIT=4)

  qkv_kernel<<<dim3(B * N / 256, 4), 256, 0, stream>>>(x, wq, bq, wk, bk, wv, bv,
                                                       bo, qT, kT, vbf, out);
  stats_kernel<<<dim3(N / 64, B, MSPLIT), 256, 0, stream>>>(qT, kT, psum);
  attn_kernel<<<dim3(N / 256, B, ZSPLIT), 256, 0, stream>>>(qT, kT, vbf, wo, psum, out);
}